// Round 13
// baseline (45.945 us; speedup 1.0000x reference)
//
#include <hip/hip_runtime.h>

#define HIDDEN 64
#define LOGB 9
#define BSN 512          // nodes per bucket
#define NTILES 256       // sort tiles (blocks)
#define NTS 1024         // threads for the sort kernel
#define NTE 1024         // threads for bucket (consumer) kernels
#define MAXBK 256        // max buckets (LDS cell staging)
#define CAPT 64          // capacity per (bucket,tile) cell; mean ~24 here
#define SRCBITS 17       // src id fits in 17 bits (n <= 131072)
#define SENT 0xFFFFFFFFu
#define GL 8             // lanes per cell-group in sort flush
#define SGRP (NTS / GL)  // cell-groups per sort block (flush)

// ---- K1: single-pass bucket-sort, LDS-staged, fully-padded coalesced flush -
// Cell (g,t) occupies sw[(g*NTILES+t)*CAPT ...CAPT), ALL CAPT words valid:
// real edges then SENT padding. Consumer row for bucket g is contiguous
// NTILES*CAPT words and is consumed by pure linear streaming.
__global__ __launch_bounds__(NTS) void k_sort(const int* __restrict__ src,
                                              const int* __restrict__ dst,
                                              int e, int nbuck,
                                              unsigned* __restrict__ sw) {
    __shared__ int lcnt[MAXBK];
    __shared__ unsigned cells[MAXBK * CAPT];   // 64 KB at nbuck=256
    const int t = blockIdx.x, tid = threadIdx.x;
    for (int g = tid; g < nbuck; g += NTS) lcnt[g] = 0;
    __syncthreads();
    const int Q = e >> 2;
    const int qlo = (int)((long long)Q * t / NTILES);
    const int qhi = (int)((long long)Q * (t + 1) / NTILES);
    for (int q = qlo + tid; q < qhi; q += NTS) {
        int4 s4 = ((const int4*)src)[q];
        int4 d4 = ((const int4*)dst)[q];
        { int d = d4.x, g = d >> LOGB; int p = atomicAdd(&lcnt[g], 1);
          if (p < CAPT) cells[g * CAPT + p] =
              ((unsigned)(d & (BSN - 1)) << SRCBITS) | (unsigned)s4.x; }
        { int d = d4.y, g = d >> LOGB; int p = atomicAdd(&lcnt[g], 1);
          if (p < CAPT) cells[g * CAPT + p] =
              ((unsigned)(d & (BSN - 1)) << SRCBITS) | (unsigned)s4.y; }
        { int d = d4.z, g = d >> LOGB; int p = atomicAdd(&lcnt[g], 1);
          if (p < CAPT) cells[g * CAPT + p] =
              ((unsigned)(d & (BSN - 1)) << SRCBITS) | (unsigned)s4.z; }
        { int d = d4.w, g = d >> LOGB; int p = atomicAdd(&lcnt[g], 1);
          if (p < CAPT) cells[g * CAPT + p] =
              ((unsigned)(d & (BSN - 1)) << SRCBITS) | (unsigned)s4.w; }
    }
    if (t == 0) {  // tail edges (e % 4)
        for (int i = (Q << 2) + tid; i < e; i += NTS) {
            int d = dst[i], g = d >> LOGB;
            int p = atomicAdd(&lcnt[g], 1);
            if (p < CAPT) cells[g * CAPT + p] =
                ((unsigned)(d & (BSN - 1)) << SRCBITS) | (unsigned)src[i];
        }
    }
    __syncthreads();
    // flush: pad every cell to CAPT with SENT, then copy all CAPT words
    const int grp = tid >> 3, lg = tid & (GL - 1);
    for (int g = grp; g < nbuck; g += SGRP) {
        int cnt = lcnt[g]; if (cnt > CAPT) cnt = CAPT;
        for (int p = cnt + lg; p < CAPT; p += GL) cells[g * CAPT + p] = SENT;
        // 8-lane group operates within one wave: LDS write->read ordered
        const uint4* lc = (const uint4*)&cells[g * CAPT];
        uint4* gseg = (uint4*)(sw + ((size_t)g * NTILES + t) * CAPT);
#pragma unroll
        for (int q = lg; q < (CAPT >> 2); q += GL) gseg[q] = lc[q];
    }
}

// ---- K2: degree -> dinv, xs  (one block per bucket, linear stream) ---------
__global__ __launch_bounds__(NTE) void k_deg_prep(const unsigned* __restrict__ sw,
                                                  const float* __restrict__ x,
                                                  float* __restrict__ dinv,
                                                  float* __restrict__ xs,
                                                  int n) {
    __shared__ float lacc[BSN];
    const int g = blockIdx.x, tid = threadIdx.x;
    if (tid < BSN) lacc[tid] = 0.0f;
    __syncthreads();
    const uint4* row = (const uint4*)(sw + (size_t)g * NTILES * CAPT);
    const int nq = NTILES * CAPT / 4;
    for (int q = tid; q < nq; q += NTE) {
        uint4 w4 = row[q];
        unsigned l0 = w4.x >> SRCBITS; if (l0 < BSN) atomicAdd(&lacc[l0], 1.0f);
        unsigned l1 = w4.y >> SRCBITS; if (l1 < BSN) atomicAdd(&lacc[l1], 1.0f);
        unsigned l2 = w4.z >> SRCBITS; if (l2 < BSN) atomicAdd(&lacc[l2], 1.0f);
        unsigned l3 = w4.w >> SRCBITS; if (l3 < BSN) atomicAdd(&lacc[l3], 1.0f);
    }
    __syncthreads();
    const int node = (g << LOGB) + tid;
    if (tid < BSN && node < n) {
        float d = rsqrtf(1.0f + lacc[tid]);   // +1 = self-loop
        dinv[node] = d;
        xs[node] = x[node] * d;
    }
}

// ---- K3: scatter xs -> agg -> MLP -> h2s (linear stream) -------------------
__global__ __launch_bounds__(NTE) void k_scat_mlp(const unsigned* __restrict__ sw,
    const float* __restrict__ dinv, const float* __restrict__ xs,
    const float* __restrict__ W1, const float* __restrict__ b1,
    const float* __restrict__ W2, float* __restrict__ h2s, int n) {
    __shared__ float lacc[BSN];
    __shared__ float swt[3 * HIDDEN];
    const int g = blockIdx.x, tid = threadIdx.x;
    if (tid < BSN) lacc[tid] = 0.0f;
    if (tid >= BSN && tid < BSN + 3 * HIDDEN) {
        int j = tid - BSN;
        swt[j] = (j < HIDDEN) ? W1[j]
               : (j < 2 * HIDDEN) ? b1[j - HIDDEN] : W2[j - 2 * HIDDEN];
    }
    __syncthreads();
    const unsigned SM = (1u << SRCBITS) - 1;
    const uint4* row = (const uint4*)(sw + (size_t)g * NTILES * CAPT);
    const int nq = NTILES * CAPT / 4;
    for (int q = tid; q < nq; q += NTE) {
        uint4 w4 = row[q];
        unsigned l0 = w4.x >> SRCBITS; if (l0 < BSN) atomicAdd(&lacc[l0], xs[w4.x & SM]);
        unsigned l1 = w4.y >> SRCBITS; if (l1 < BSN) atomicAdd(&lacc[l1], xs[w4.y & SM]);
        unsigned l2 = w4.z >> SRCBITS; if (l2 < BSN) atomicAdd(&lacc[l2], xs[w4.z & SM]);
        unsigned l3 = w4.w >> SRCBITS; if (l3 < BSN) atomicAdd(&lacc[l3], xs[w4.w & SM]);
    }
    __syncthreads();
    const int node = (g << LOGB) + tid;
    if (tid < BSN && node < n) {
        float di = dinv[node];
        float s1 = di * (lacc[tid] + xs[node]);  // xs = self-loop term
        float h = 0.0f;
#pragma unroll
        for (int j = 0; j < HIDDEN; ++j)
            h += fmaxf(fmaf(s1, swt[j], swt[HIDDEN + j]), 0.0f) * swt[2 * HIDDEN + j];
        h2s[node] = h * di;
    }
}

// ---- K4: scatter h2s -> agg -> out (linear stream) -------------------------
__global__ __launch_bounds__(NTE) void k_scat_out(const unsigned* __restrict__ sw,
    const float* __restrict__ dinv, const float* __restrict__ h2s,
    const float* __restrict__ b2, float* __restrict__ out, int n) {
    __shared__ float lacc[BSN];
    const int g = blockIdx.x, tid = threadIdx.x;
    if (tid < BSN) lacc[tid] = 0.0f;
    __syncthreads();
    const unsigned SM = (1u << SRCBITS) - 1;
    const uint4* row = (const uint4*)(sw + (size_t)g * NTILES * CAPT);
    const int nq = NTILES * CAPT / 4;
    for (int q = tid; q < nq; q += NTE) {
        uint4 w4 = row[q];
        unsigned l0 = w4.x >> SRCBITS; if (l0 < BSN) atomicAdd(&lacc[l0], h2s[w4.x & SM]);
        unsigned l1 = w4.y >> SRCBITS; if (l1 < BSN) atomicAdd(&lacc[l1], h2s[w4.y & SM]);
        unsigned l2 = w4.z >> SRCBITS; if (l2 < BSN) atomicAdd(&lacc[l2], h2s[w4.z & SM]);
        unsigned l3 = w4.w >> SRCBITS; if (l3 < BSN) atomicAdd(&lacc[l3], h2s[w4.w & SM]);
    }
    __syncthreads();
    const int node = (g << LOGB) + tid;
    if (tid < BSN && node < n)
        out[node] = dinv[node] * (lacc[tid] + h2s[node]) + b2[0];
}

// ---------------- fallback: single-copy global-atomic path ----------------
__global__ void f_init(float* deg, float* agg, int n) {
    int i = blockIdx.x * blockDim.x + threadIdx.x;
    if (i < n) { deg[i] = 1.0f; agg[i] = 0.0f; }
}
__global__ void f_deg(const int* __restrict__ dst, float* deg, int e) {
    int i = blockIdx.x * blockDim.x + threadIdx.x;
    if (i < e) atomicAdd(&deg[dst[i]], 1.0f);
}
__global__ void f_prep(const float* __restrict__ x, float* deg,
                       float* __restrict__ xs, int n) {
    int i = blockIdx.x * blockDim.x + threadIdx.x;
    if (i < n) { float d = rsqrtf(deg[i]); deg[i] = d; xs[i] = x[i] * d; }
}
__global__ void f_scat(const int* __restrict__ src, const int* __restrict__ dst,
                       const float* __restrict__ vals, float* agg, int e) {
    int i = blockIdx.x * blockDim.x + threadIdx.x;
    if (i < e) atomicAdd(&agg[dst[i]], vals[src[i]]);
}
__global__ void f_mlp(const float* __restrict__ dinv, const float* __restrict__ xs,
                      float* agg, const float* __restrict__ W1,
                      const float* __restrict__ b1, const float* __restrict__ W2,
                      float* __restrict__ h2s, int n) {
    __shared__ float sW1[HIDDEN], sb1[HIDDEN], sW2[HIDDEN];
    if (threadIdx.x < HIDDEN) {
        sW1[threadIdx.x] = W1[threadIdx.x];
        sb1[threadIdx.x] = b1[threadIdx.x];
        sW2[threadIdx.x] = W2[threadIdx.x];
    }
    __syncthreads();
    int i = blockIdx.x * blockDim.x + threadIdx.x;
    if (i >= n) return;
    float di = dinv[i];
    float s1 = di * (agg[i] + xs[i]);
    agg[i] = 0.0f;
    float h = 0.0f;
#pragma unroll
    for (int j = 0; j < HIDDEN; ++j)
        h += fmaxf(fmaf(s1, sW1[j], sb1[j]), 0.0f) * sW2[j];
    h2s[i] = h * di;
}
__global__ void f_out(const float* __restrict__ dinv, const float* __restrict__ h2s,
                      const float* __restrict__ agg, const float* __restrict__ b2,
                      float* __restrict__ out, int n) {
    int i = blockIdx.x * blockDim.x + threadIdx.x;
    if (i < n) out[i] = dinv[i] * (agg[i] + h2s[i]) + b2[0];
}

// ---------------------------------------------------------------------------
extern "C" void kernel_launch(void* const* d_in, const int* in_sizes, int n_in,
                              void* d_out, int out_size, void* d_ws, size_t ws_size,
                              hipStream_t stream) {
    const float* x  = (const float*)d_in[0];
    const int*   ei = (const int*)d_in[1];   // [2, E] int32
    const float* W1 = (const float*)d_in[2];
    const float* b1 = (const float*)d_in[3];
    const float* W2 = (const float*)d_in[4];
    const float* b2 = (const float*)d_in[5];
    float* out = (float*)d_out;

    const int n = in_sizes[0];
    const int e = in_sizes[1] / 2;
    const int* src = ei;
    const int* dst = ei + e;

    const int nbuck = (n + BSN - 1) >> LOGB;
    // ws: dinv[n], xs[n], h2s[n] | sw[nbuck*NTILES*CAPT]
    const size_t need = ((size_t)3 * n + (size_t)nbuck * NTILES * CAPT)
                        * sizeof(int);
    // require mean cell occupancy <= CAPT/2 so overflow is statistically nil
    const bool cap_ok = (long long)e * 2 <= (long long)NTILES * nbuck * CAPT;

    if (nbuck >= 1 && nbuck <= MAXBK && n <= (1 << SRCBITS) &&
        e >= 4 && cap_ok && ws_size >= need) {
        float* dinv  = (float*)d_ws;
        float* xs    = dinv + n;
        float* h2s   = xs + n;
        unsigned* sw = (unsigned*)(h2s + n);

        k_sort    <<<NTILES, NTS, 0, stream>>>(src, dst, e, nbuck, sw);
        k_deg_prep<<<nbuck,  NTE, 0, stream>>>(sw, x, dinv, xs, n);
        k_scat_mlp<<<nbuck,  NTE, 0, stream>>>(sw, dinv, xs, W1, b1, W2, h2s, n);
        k_scat_out<<<nbuck,  NTE, 0, stream>>>(sw, dinv, h2s, b2, out, n);
    } else {
        const int BT = 256;
        const int gn = (n + BT - 1) / BT;
        const int ge = (e + BT - 1) / BT;
        float* dinv = (float*)d_ws;   // holds deg then dinv
        float* xs   = dinv + n;
        float* h2s  = xs + n;
        float* agg  = h2s + n;
        f_init<<<gn, BT, 0, stream>>>(dinv, agg, n);
        f_deg <<<ge, BT, 0, stream>>>(dst, dinv, e);
        f_prep<<<gn, BT, 0, stream>>>(x, dinv, xs, n);
        f_scat<<<ge, BT, 0, stream>>>(src, dst, xs, agg, e);
        f_mlp <<<gn, BT, 0, stream>>>(dinv, xs, agg, W1, b1, W2, h2s, n);
        f_scat<<<ge, BT, 0, stream>>>(src, dst, h2s, agg, e);
        f_out <<<gn, BT, 0, stream>>>(dinv, h2s, agg, b2, out, n);
    }
}

// Round 14
// 43.962 us; speedup vs baseline: 1.0451x; 1.0451x over previous
//
#include <hip/hip_runtime.h>

#define HIDDEN 64
#define LOGB 9
#define BSN 512          // nodes per bucket
#define NTILES 128       // sort tiles (blocks)
#define NTS 1024         // threads for the sort kernel
#define NTE 1024         // threads for bucket (consumer) kernels
#define MAXBK 200        // max buckets (LDS cell staging: 200*96*4 = 76.8 KB)
#define CAPT 96          // capacity per (bucket,tile) cell; mean ~48 here
#define SRCBITS 17       // src id fits in 17 bits (n <= 131072)
#define SENT 0xFFFFFFFFu
#define GL 8             // lanes per cell-group
#define NGRP (NTE / GL)  // cell-groups per consumer block
#define SGRP (NTS / GL)  // cell-groups per sort block (flush)

// ---- K1: single-pass bucket-sort, LDS-staged, coalesced cell flush ---------
// Cell (g,t) at sw[(g*NTILES+t)*CAPT ...]; exact count counts[g*NTILES+t];
// tail padded with SENT to a multiple of 4 for clean uint4 consumption.
__global__ __launch_bounds__(NTS) void k_sort(const int* __restrict__ src,
                                              const int* __restrict__ dst,
                                              int e, int nbuck,
                                              unsigned* __restrict__ sw,
                                              int* __restrict__ counts) {
    __shared__ int lcnt[MAXBK];
    __shared__ unsigned cells[MAXBK * CAPT];
    const int t = blockIdx.x, tid = threadIdx.x;
    for (int g = tid; g < nbuck; g += NTS) lcnt[g] = 0;
    __syncthreads();
    const int Q = e >> 2;
    const int qlo = (int)((long long)Q * t / NTILES);
    const int qhi = (int)((long long)Q * (t + 1) / NTILES);
    for (int q = qlo + tid; q < qhi; q += NTS) {
        int4 s4 = ((const int4*)src)[q];
        int4 d4 = ((const int4*)dst)[q];
        { int d = d4.x, g = d >> LOGB; int p = atomicAdd(&lcnt[g], 1);
          if (p < CAPT) cells[g * CAPT + p] =
              ((unsigned)(d & (BSN - 1)) << SRCBITS) | (unsigned)s4.x; }
        { int d = d4.y, g = d >> LOGB; int p = atomicAdd(&lcnt[g], 1);
          if (p < CAPT) cells[g * CAPT + p] =
              ((unsigned)(d & (BSN - 1)) << SRCBITS) | (unsigned)s4.y; }
        { int d = d4.z, g = d >> LOGB; int p = atomicAdd(&lcnt[g], 1);
          if (p < CAPT) cells[g * CAPT + p] =
              ((unsigned)(d & (BSN - 1)) << SRCBITS) | (unsigned)s4.z; }
        { int d = d4.w, g = d >> LOGB; int p = atomicAdd(&lcnt[g], 1);
          if (p < CAPT) cells[g * CAPT + p] =
              ((unsigned)(d & (BSN - 1)) << SRCBITS) | (unsigned)s4.w; }
    }
    if (t == 0) {  // tail edges (e % 4)
        for (int i = (Q << 2) + tid; i < e; i += NTS) {
            int d = dst[i], g = d >> LOGB;
            int p = atomicAdd(&lcnt[g], 1);
            if (p < CAPT) cells[g * CAPT + p] =
                ((unsigned)(d & (BSN - 1)) << SRCBITS) | (unsigned)src[i];
        }
    }
    __syncthreads();
    // flush: 8-lane groups pad to multiple-of-4 + copy cells as uint4 bursts
    const int grp = tid >> 3, lg = tid & (GL - 1);
    for (int g = grp; g < nbuck; g += SGRP) {
        int cnt = lcnt[g]; if (cnt > CAPT) cnt = CAPT;
        const int cp = (cnt + 3) & ~3;
        for (int p = cnt + lg; p < cp; p += GL) cells[g * CAPT + p] = SENT;
        // 8-lane group lives in one wave: LDS write->read ordering is safe
        const uint4* lc = (const uint4*)&cells[g * CAPT];
        uint4* gseg = (uint4*)(sw + ((size_t)g * NTILES + t) * CAPT);
        for (int q = lg; q < (cp >> 2); q += GL) gseg[q] = lc[q];
        if (lg == 0) counts[g * NTILES + t] = cnt;
    }
}

// ---- K2: degree -> dinv, xs  (one block per bucket) ------------------------
__global__ __launch_bounds__(NTE) void k_deg_prep(const unsigned* __restrict__ sw,
                                                  const int* __restrict__ counts,
                                                  const float* __restrict__ x,
                                                  float* __restrict__ dinv,
                                                  float* __restrict__ xs,
                                                  int n) {
    __shared__ float lacc[BSN];
    __shared__ int scnt[NTILES];
    const int g = blockIdx.x, tid = threadIdx.x;
    if (tid < BSN) lacc[tid] = 0.0f;
    if (tid < NTILES) scnt[tid] = counts[g * NTILES + tid];
    __syncthreads();
    const int grp = tid >> 3, lg = tid & (GL - 1);
    for (int t = grp; t < NTILES; t += NGRP) {
        const int cnt = scnt[t];
        const uint4* seg4 = (const uint4*)(sw + ((size_t)g * NTILES + t) * CAPT);
        for (int q = lg; q < ((cnt + 3) >> 2); q += GL) {
            uint4 w4 = seg4[q];
            unsigned l0 = w4.x >> SRCBITS; if (l0 < BSN) atomicAdd(&lacc[l0], 1.0f);
            unsigned l1 = w4.y >> SRCBITS; if (l1 < BSN) atomicAdd(&lacc[l1], 1.0f);
            unsigned l2 = w4.z >> SRCBITS; if (l2 < BSN) atomicAdd(&lacc[l2], 1.0f);
            unsigned l3 = w4.w >> SRCBITS; if (l3 < BSN) atomicAdd(&lacc[l3], 1.0f);
        }
    }
    __syncthreads();
    const int node = (g << LOGB) + tid;
    if (tid < BSN && node < n) {
        float d = rsqrtf(1.0f + lacc[tid]);   // +1 = self-loop
        dinv[node] = d;
        xs[node] = x[node] * d;
    }
}

// ---- K3: scatter xs -> agg -> MLP -> h2s -----------------------------------
__global__ __launch_bounds__(NTE) void k_scat_mlp(const unsigned* __restrict__ sw,
    const int* __restrict__ counts, const float* __restrict__ dinv,
    const float* __restrict__ xs, const float* __restrict__ W1,
    const float* __restrict__ b1, const float* __restrict__ W2,
    float* __restrict__ h2s, int n) {
    __shared__ float lacc[BSN];
    __shared__ float swt[3 * HIDDEN];
    __shared__ int scnt[NTILES];
    const int g = blockIdx.x, tid = threadIdx.x;
    if (tid < BSN) lacc[tid] = 0.0f;
    if (tid < NTILES) scnt[tid] = counts[g * NTILES + tid];
    if (tid >= BSN && tid < BSN + 3 * HIDDEN) {
        int j = tid - BSN;
        swt[j] = (j < HIDDEN) ? W1[j]
               : (j < 2 * HIDDEN) ? b1[j - HIDDEN] : W2[j - 2 * HIDDEN];
    }
    __syncthreads();
    const unsigned SM = (1u << SRCBITS) - 1;
    const int grp = tid >> 3, lg = tid & (GL - 1);
    for (int t = grp; t < NTILES; t += NGRP) {
        const int cnt = scnt[t];
        const uint4* seg4 = (const uint4*)(sw + ((size_t)g * NTILES + t) * CAPT);
        for (int q = lg; q < ((cnt + 3) >> 2); q += GL) {
            uint4 w4 = seg4[q];
            unsigned l0 = w4.x >> SRCBITS; if (l0 < BSN) atomicAdd(&lacc[l0], xs[w4.x & SM]);
            unsigned l1 = w4.y >> SRCBITS; if (l1 < BSN) atomicAdd(&lacc[l1], xs[w4.y & SM]);
            unsigned l2 = w4.z >> SRCBITS; if (l2 < BSN) atomicAdd(&lacc[l2], xs[w4.z & SM]);
            unsigned l3 = w4.w >> SRCBITS; if (l3 < BSN) atomicAdd(&lacc[l3], xs[w4.w & SM]);
        }
    }
    __syncthreads();
    const int node = (g << LOGB) + tid;
    if (tid < BSN && node < n) {
        float di = dinv[node];
        float s1 = di * (lacc[tid] + xs[node]);  // xs = self-loop term
        float h = 0.0f;
#pragma unroll
        for (int j = 0; j < HIDDEN; ++j)
            h += fmaxf(fmaf(s1, swt[j], swt[HIDDEN + j]), 0.0f) * swt[2 * HIDDEN + j];
        h2s[node] = h * di;
    }
}

// ---- K4: scatter h2s -> agg -> out -----------------------------------------
__global__ __launch_bounds__(NTE) void k_scat_out(const unsigned* __restrict__ sw,
    const int* __restrict__ counts, const float* __restrict__ dinv,
    const float* __restrict__ h2s, const float* __restrict__ b2,
    float* __restrict__ out, int n) {
    __shared__ float lacc[BSN];
    __shared__ int scnt[NTILES];
    const int g = blockIdx.x, tid = threadIdx.x;
    if (tid < BSN) lacc[tid] = 0.0f;
    if (tid < NTILES) scnt[tid] = counts[g * NTILES + tid];
    __syncthreads();
    const unsigned SM = (1u << SRCBITS) - 1;
    const int grp = tid >> 3, lg = tid & (GL - 1);
    for (int t = grp; t < NTILES; t += NGRP) {
        const int cnt = scnt[t];
        const uint4* seg4 = (const uint4*)(sw + ((size_t)g * NTILES + t) * CAPT);
        for (int q = lg; q < ((cnt + 3) >> 2); q += GL) {
            uint4 w4 = seg4[q];
            unsigned l0 = w4.x >> SRCBITS; if (l0 < BSN) atomicAdd(&lacc[l0], h2s[w4.x & SM]);
            unsigned l1 = w4.y >> SRCBITS; if (l1 < BSN) atomicAdd(&lacc[l1], h2s[w4.y & SM]);
            unsigned l2 = w4.z >> SRCBITS; if (l2 < BSN) atomicAdd(&lacc[l2], h2s[w4.z & SM]);
            unsigned l3 = w4.w >> SRCBITS; if (l3 < BSN) atomicAdd(&lacc[l3], h2s[w4.w & SM]);
        }
    }
    __syncthreads();
    const int node = (g << LOGB) + tid;
    if (tid < BSN && node < n)
        out[node] = dinv[node] * (lacc[tid] + h2s[node]) + b2[0];
}

// ---------------- fallback: single-copy global-atomic path ----------------
__global__ void f_init(float* deg, float* agg, int n) {
    int i = blockIdx.x * blockDim.x + threadIdx.x;
    if (i < n) { deg[i] = 1.0f; agg[i] = 0.0f; }
}
__global__ void f_deg(const int* __restrict__ dst, float* deg, int e) {
    int i = blockIdx.x * blockDim.x + threadIdx.x;
    if (i < e) atomicAdd(&deg[dst[i]], 1.0f);
}
__global__ void f_prep(const float* __restrict__ x, float* deg,
                       float* __restrict__ xs, int n) {
    int i = blockIdx.x * blockDim.x + threadIdx.x;
    if (i < n) { float d = rsqrtf(deg[i]); deg[i] = d; xs[i] = x[i] * d; }
}
__global__ void f_scat(const int* __restrict__ src, const int* __restrict__ dst,
                       const float* __restrict__ vals, float* agg, int e) {
    int i = blockIdx.x * blockDim.x + threadIdx.x;
    if (i < e) atomicAdd(&agg[dst[i]], vals[src[i]]);
}
__global__ void f_mlp(const float* __restrict__ dinv, const float* __restrict__ xs,
                      float* agg, const float* __restrict__ W1,
                      const float* __restrict__ b1, const float* __restrict__ W2,
                      float* __restrict__ h2s, int n) {
    __shared__ float sW1[HIDDEN], sb1[HIDDEN], sW2[HIDDEN];
    if (threadIdx.x < HIDDEN) {
        sW1[threadIdx.x] = W1[threadIdx.x];
        sb1[threadIdx.x] = b1[threadIdx.x];
        sW2[threadIdx.x] = W2[threadIdx.x];
    }
    __syncthreads();
    int i = blockIdx.x * blockDim.x + threadIdx.x;
    if (i >= n) return;
    float di = dinv[i];
    float s1 = di * (agg[i] + xs[i]);
    agg[i] = 0.0f;
    float h = 0.0f;
#pragma unroll
    for (int j = 0; j < HIDDEN; ++j)
        h += fmaxf(fmaf(s1, sW1[j], sb1[j]), 0.0f) * sW2[j];
    h2s[i] = h * di;
}
__global__ void f_out(const float* __restrict__ dinv, const float* __restrict__ h2s,
                      const float* __restrict__ agg, const float* __restrict__ b2,
                      float* __restrict__ out, int n) {
    int i = blockIdx.x * blockDim.x + threadIdx.x;
    if (i < n) out[i] = dinv[i] * (agg[i] + h2s[i]) + b2[0];
}

// ---------------------------------------------------------------------------
extern "C" void kernel_launch(void* const* d_in, const int* in_sizes, int n_in,
                              void* d_out, int out_size, void* d_ws, size_t ws_size,
                              hipStream_t stream) {
    const float* x  = (const float*)d_in[0];
    const int*   ei = (const int*)d_in[1];   // [2, E] int32
    const float* W1 = (const float*)d_in[2];
    const float* b1 = (const float*)d_in[3];
    const float* W2 = (const float*)d_in[4];
    const float* b2 = (const float*)d_in[5];
    float* out = (float*)d_out;

    const int n = in_sizes[0];
    const int e = in_sizes[1] / 2;
    const int* src = ei;
    const int* dst = ei + e;

    const int nbuck = (n + BSN - 1) >> LOGB;
    // ws: dinv[n], xs[n], h2s[n] | sw[nbuck*NTILES*CAPT] | counts[nbuck*NTILES]
    const size_t need = ((size_t)3 * n + (size_t)nbuck * NTILES * CAPT
                         + (size_t)nbuck * NTILES) * sizeof(int);
    // require mean cell occupancy <= CAPT/2 so overflow is statistically nil
    const bool cap_ok = (long long)e * 2 <= (long long)NTILES * nbuck * CAPT;

    if (nbuck >= 1 && nbuck <= MAXBK && n <= (1 << SRCBITS) &&
        e >= 4 && cap_ok && ws_size >= need) {
        float* dinv  = (float*)d_ws;
        float* xs    = dinv + n;
        float* h2s   = xs + n;
        unsigned* sw = (unsigned*)(h2s + n);
        int* counts  = (int*)(sw + (size_t)nbuck * NTILES * CAPT);

        k_sort    <<<NTILES, NTS, 0, stream>>>(src, dst, e, nbuck, sw, counts);
        k_deg_prep<<<nbuck,  NTE, 0, stream>>>(sw, counts, x, dinv, xs, n);
        k_scat_mlp<<<nbuck,  NTE, 0, stream>>>(sw, counts, dinv, xs,
                                               W1, b1, W2, h2s, n);
        k_scat_out<<<nbuck,  NTE, 0, stream>>>(sw, counts, dinv, h2s,
                                               b2, out, n);
    } else {
        const int BT = 256;
        const int gn = (n + BT - 1) / BT;
        const int ge = (e + BT - 1) / BT;
        float* dinv = (float*)d_ws;   // holds deg then dinv
        float* xs   = dinv + n;
        float* h2s  = xs + n;
        float* agg  = h2s + n;
        f_init<<<gn, BT, 0, stream>>>(dinv, agg, n);
        f_deg <<<ge, BT, 0, stream>>>(dst, dinv, e);
        f_prep<<<gn, BT, 0, stream>>>(x, dinv, xs, n);
        f_scat<<<ge, BT, 0, stream>>>(src, dst, xs, agg, e);
        f_mlp <<<gn, BT, 0, stream>>>(dinv, xs, agg, W1, b1, W2, h2s, n);
        f_scat<<<ge, BT, 0, stream>>>(src, dst, h2s, agg, e);
        f_out <<<gn, BT, 0, stream>>>(dinv, h2s, agg, b2, out, n);
    }
}